// Round 3
// baseline (208.121 us; speedup 1.0000x reference)
//
#include <hip/hip_runtime.h>
#include <math.h>

// ETM forward. B=1024 S=512 V=50000 E=300 H=800 T=50.
// ka: [fused] rhoh=bf16(rho) cast (8 floats/thread) + zero topicsumR/loss + B-frags
// kb: [fused] k4 betaU=exp(rhoh@alpha^T) + k1 gather via global_load_lds DMA:
//     4-row batches double-buffered in LDS, counted s_waitcnt vmcnt(4) keeps
//     next batch in flight (HW-enforced pipelining; compiler refused reg version)
// kx: xbar = (sum_r xbarP)/n -> bf16 xsg (once, not 13x inside k2m)
// k2m: hbh = bf16(relu(xsg@W1+b1)) via MFMA
// k3: mu/lv via MFMA -> LDS -> softmax/theta/kl
// k6: recon + loss

#define Bn 1024
#define Sn 512
#define Vn 50000
#define En 300
#define Hn 800
#define Tn 50
#define KP 320             // padded K for E-dim (10 tiles of 32)
#define BSTR 64            // betaU bf16 row stride (ushorts) = 128 B
#define W1FRAG_N (50 * 10 * 64 * 8)
#define WFRAG_N  (8 * 25 * 64 * 8)
#define NRANGE 8
#define VRANGE (Vn / NRANGE)
#define CASTB 7813                             // ceil(Vn*(KP/8)/256)
#define K4B (Vn / 16)                          // 3125 k4 blocks

typedef __bf16 bf16x8 __attribute__((ext_vector_type(8)));
typedef float  f32x4  __attribute__((ext_vector_type(4)));
typedef float  f32x2  __attribute__((ext_vector_type(2)));

__device__ __forceinline__ float waveReduceSum(float v) {
    #pragma unroll
    for (int off = 32; off > 0; off >>= 1) v += __shfl_xor(v, off, 64);
    return v;
}
__device__ __forceinline__ float waveReduceMax(float v) {
    #pragma unroll
    for (int off = 32; off > 0; off >>= 1) v = fmaxf(v, __shfl_xor(v, off, 64));
    return v;
}
__device__ __forceinline__ unsigned short f2bf(float x) {
    unsigned u = __float_as_uint(x);
    return (unsigned short)((u + 0x7FFFu + ((u >> 16) & 1u)) >> 16);
}
__device__ __forceinline__ float bf_lo(unsigned u) { return __uint_as_float(u << 16); }
__device__ __forceinline__ float bf_hi(unsigned u) { return __uint_as_float(u & 0xFFFF0000u); }
__device__ __forceinline__ int lane_prefix(unsigned long long m) {
    return __builtin_amdgcn_mbcnt_hi((unsigned)(m >> 32),
           __builtin_amdgcn_mbcnt_lo((unsigned)m, 0));
}
// async global->LDS DMA, 16B per active lane; LDS dest = base + lane*16
__device__ __forceinline__ void gl_lds16(const void* g, void* l) {
    __builtin_amdgcn_global_load_lds(
        (const __attribute__((address_space(1))) void*)g,
        (__attribute__((address_space(3))) void*)l, 16, 0, 0);
}

#define PKACC(u) { \
    c0 += (f32x2){bf_lo((u).x), bf_hi((u).x)}; \
    c1 += (f32x2){bf_lo((u).y), bf_hi((u).y)}; \
    c2 += (f32x2){bf_lo((u).z), bf_hi((u).z)}; \
    c3 += (f32x2){bf_lo((u).w), bf_hi((u).w)}; }

// Fused: blocks [0,CASTB) stream-cast rho->rhoh (8 f32 -> 8 bf16 per thread);
// the rest zero topicsumR/loss and build alpha/W1/[Wmu|Wlv] MFMA B-frags.
__global__ __launch_bounds__(256) void ka_init(
        const float4* __restrict__ rho4, unsigned short* __restrict__ rhoh,
        const float* __restrict__ alpha, const float* __restrict__ W1,
        const float* __restrict__ Wmu, const float* __restrict__ Wlv,
        unsigned short* __restrict__ bfrag, unsigned short* __restrict__ w1frag,
        unsigned short* __restrict__ wfrag, float* __restrict__ topicsumR,
        float* __restrict__ loss) {
    if (blockIdx.x < CASTB) {
        const int i = blockIdx.x * 256 + threadIdx.x;
        if (i < Vn * (KP / 8)) {
            int v = i / (KP / 8), s8 = i - v * (KP / 8);
            int c = s8 * 8;
            ushort4 o0 = {0, 0, 0, 0}, o1 = {0, 0, 0, 0};
            if (c < En) {
                float4 r = rho4[v * (En / 4) + s8 * 2];
                o0.x = f2bf(r.x); o0.y = f2bf(r.y); o0.z = f2bf(r.z); o0.w = f2bf(r.w);
            }
            if (c + 4 < En) {
                float4 r = rho4[v * (En / 4) + s8 * 2 + 1];
                o1.x = f2bf(r.x); o1.y = f2bf(r.y); o1.z = f2bf(r.z); o1.w = f2bf(r.w);
            }
            uint4 st;
            st.x = (unsigned)o0.x | ((unsigned)o0.y << 16);
            st.y = (unsigned)o0.z | ((unsigned)o0.w << 16);
            st.z = (unsigned)o1.x | ((unsigned)o1.y << 16);
            st.w = (unsigned)o1.z | ((unsigned)o1.w << 16);
            *(uint4*)(rhoh + (size_t)v * KP + c) = st;
        }
        return;
    }
    const int gid = (blockIdx.x - CASTB) * 256 + threadIdx.x;
    if (gid < 512) topicsumR[gid] = 0.f;
    if (gid == 520) *loss = 0.f;
    if (gid < 4 * 10 * 64 * 8) {
        int j = gid & 7;
        int lane = (gid >> 3) & 63;
        int rest = gid >> 9;               // w*10 + kt
        int kt = rest % 10, w = rest / 10;
        int t = 16 * w + (lane & 15);
        int e = kt * 32 + (lane >> 4) * 8 + j;
        bfrag[gid] = (t < Tn && e < En) ? f2bf(alpha[t * En + e]) : (unsigned short)0;
    }
    if (gid < W1FRAG_N) {
        int j = gid & 7, lane = (gid >> 3) & 63, rest = gid >> 9;
        int kt = rest % 10, nt = rest / 10;
        int e = kt * 32 + (lane >> 4) * 8 + j;
        int hcol = nt * 16 + (lane & 15);
        w1frag[gid] = (e < En) ? f2bf(W1[e * Hn + hcol]) : (unsigned short)0;
    } else {
        int g2 = gid - W1FRAG_N;
        if (g2 < WFRAG_N) {
            int j = g2 & 7, lane = (g2 >> 3) & 63, rest = g2 >> 9;
            int kt = rest % 25, nt = rest / 25;
            int k = kt * 32 + (lane >> 4) * 8 + j;        // < 800 always
            int t = (nt & 3) * 16 + (lane & 15);
            float val = 0.f;
            if (t < Tn) val = (nt < 4) ? Wmu[k * Tn + t] : Wlv[k * Tn + t];
            wfrag[g2] = f2bf(val);
        }
    }
}

// Fused k4+k1: blocks [0,K4B) = betaU MFMA tiles; rest = sliced token gather.
__global__ __launch_bounds__(256) void kb_beta_tokens(
        const unsigned short* __restrict__ rhoh,
        const unsigned short* __restrict__ bfrag,
        unsigned int* __restrict__ betaU32, float* __restrict__ topicsumR,
        const int* __restrict__ ids, int* __restrict__ toks,
        int* __restrict__ cnt, float* __restrict__ xbarP) {
    __shared__ unsigned short trans[16 * 66];   // k4 transpose (2112 B)
    __shared__ __align__(16) int sid[Sn];       // k1 range-filtered tokens
    __shared__ int sfid[Sn];                    // k1 full compaction (r==0)
    __shared__ __align__(16) float xred[4][320];            // 5120 B
    __shared__ __align__(16) char gbuf[4 * 2 * 4 * 640];    // 20480 B DMA strips
    __shared__ int scount, sfull;
    const int tid = threadIdx.x;
    const int wave = tid >> 6, lane = tid & 63;

    if (blockIdx.x < K4B) {
        // ---- k4: betaU tile (16 v), wave = topic tile ----
        const int quad = lane >> 4, l15 = lane & 15;
        const int v0 = blockIdx.x * 16;
        const unsigned short* arow = rhoh + (size_t)(v0 + l15) * KP + quad * 8;
        f32x4 acc = {0.f, 0.f, 0.f, 0.f};
        #pragma unroll
        for (int kt = 0; kt < 10; ++kt) {
            bf16x8 a = *(const bf16x8*)(arow + kt * 32);
            bf16x8 bv = *(const bf16x8*)(bfrag + ((wave * 10 + kt) * 64 + lane) * 8);
            acc = __builtin_amdgcn_mfma_f32_16x16x32_bf16(a, bv, acc, 0, 0, 0);
        }
        float ts = 0.f;
        #pragma unroll
        for (int r = 0; r < 4; ++r) {
            float ev = expf(acc[r]);
            ts += ev;
            trans[(quad * 4 + r) * 66 + 16 * wave + l15] = f2bf(ev);
        }
        ts += __shfl_xor(ts, 16, 64);
        ts += __shfl_xor(ts, 32, 64);
        const int t = 16 * wave + l15;
        if (lane < 16 && t < Tn)
            atomicAdd(&topicsumR[(blockIdx.x & 7) * 64 + t], ts);
        __syncthreads();
        unsigned int* dst = betaU32 + (size_t)v0 * 32;
        const unsigned int* tr32 = (const unsigned int*)trans;
        for (int i = tid; i < 16 * 32; i += 256)
            dst[i] = tr32[(i >> 5) * 33 + (i & 31)];
        return;
    }
    // ---- k1: doc-range gather ----
    const int blk = blockIdx.x - K4B;
    const int r = blk & (NRANGE - 1), b = blk >> 3;
    const int lo = r * VRANGE, hi = lo + VRANGE;
    if (tid == 0) { scount = 0; sfull = 0; }
    __syncthreads();
    // ballot-based compaction: one LDS atomic per wave
    #pragma unroll
    for (int s0 = 0; s0 < Sn; s0 += 256) {
        int id = ids[b * Sn + s0 + tid];
        bool val = (id != 1 && id != 2);
        bool inr = val && id >= lo && id < hi;
        unsigned long long mb = __ballot(inr);
        int pre = lane_prefix(mb);
        int wc = __popcll(mb);
        int base = 0;
        if (lane == 0 && wc) base = atomicAdd(&scount, wc);
        base = __shfl(base, 0, 64);
        if (inr) sid[base + pre] = id;
        if (r == 0) {
            unsigned long long fb = __ballot(val);
            int fpre = lane_prefix(fb);
            int fwc = __popcll(fb);
            int fbase = 0;
            if (lane == 0 && fwc) fbase = atomicAdd(&sfull, fwc);
            fbase = __shfl(fbase, 0, 64);
            if (val) sfid[fbase + fpre] = id;
        }
    }
    __syncthreads();
    if (r == 0) {
        const int nf = sfull;
        for (int i = tid; i < nf; i += 256) toks[b * Sn + i] = sfid[i];
        if (tid == 0) cnt[b] = nf;
    }
    const int m = scount;
    // --- DMA-pipelined gather: wave owns contiguous quarter of tokens,
    //     4-row batches (640B rows, lanes<40 x 16B) double-buffered in LDS,
    //     vmcnt(4) keeps next batch's 4 loads in flight.
    const char* gb = (const char*)rhoh;
    char* bufw = gbuf + wave * 5120;
    f32x2 c0 = {0.f, 0.f}, c1 = {0.f, 0.f}, c2 = {0.f, 0.f}, c3 = {0.f, 0.f};
    const int q = (m + 3) >> 2;
    const int beg = min(wave * q, m);
    const int end = min(beg + q, m);
    const int nb = (end - beg + 3) >> 2;
    const unsigned lo16 = (unsigned)lane * 16u;

    #define GISSUE(S0, DST) { \
        int r0 = sid[min((S0), end - 1)]; \
        int r1 = sid[min((S0) + 1, end - 1)]; \
        int r2 = sid[min((S0) + 2, end - 1)]; \
        int r3 = sid[min((S0) + 3, end - 1)]; \
        if (lane < 40) { \
            gl_lds16(gb + (unsigned)r0 * 640u + lo16, (DST)); \
            gl_lds16(gb + (unsigned)r1 * 640u + lo16, (DST) + 640); \
            gl_lds16(gb + (unsigned)r2 * 640u + lo16, (DST) + 1280); \
            gl_lds16(gb + (unsigned)r3 * 640u + lo16, (DST) + 1920); \
        } }

    if (nb > 0) {
        GISSUE(beg, bufw);
        for (int bch = 0; bch < nb; ++bch) {
            const int cur = bch & 1;
            if (bch + 1 < nb) {
                GISSUE(beg + (bch + 1) * 4, bufw + ((cur ^ 1) * 2560));
                asm volatile("s_waitcnt vmcnt(4)" ::: "memory");
            } else {
                asm volatile("s_waitcnt vmcnt(0)" ::: "memory");
            }
            __builtin_amdgcn_sched_barrier(0);
            if (lane < 40) {
                const char* bp = bufw + cur * 2560 + lane * 16;
                const int rem = end - (beg + bch * 4);   // >= 1
                uint4 u0 = *(const uint4*)(bp);
                PKACC(u0);
                if (rem > 1) { uint4 u = *(const uint4*)(bp + 640);  PKACC(u); }
                if (rem > 2) { uint4 u = *(const uint4*)(bp + 1280); PKACC(u); }
                if (rem > 3) { uint4 u = *(const uint4*)(bp + 1920); PKACC(u); }
            }
        }
    }
    #undef GISSUE
    if (lane < 40) {
        float* xw = &xred[wave][lane * 8];
        *(float4*)(xw)     = (float4){c0[0], c0[1], c1[0], c1[1]};
        *(float4*)(xw + 4) = (float4){c2[0], c2[1], c3[0], c3[1]};
    }
    __syncthreads();
    float* xbp = xbarP + ((size_t)b * NRANGE + r) * KP;
    for (int c = tid; c < KP; c += 256)
        xbp[c] = xred[0][c] + xred[1][c] + xred[2][c] + xred[3][c];
}

// xsg[b][e] = bf16( (sum_r xbarP[b][r][e]) / cnt[b] )  -- once, not 13x in k2m
__global__ __launch_bounds__(256) void kx_norm(
        const float* __restrict__ xbarP, const int* __restrict__ cnt,
        unsigned short* __restrict__ xsg) {
    const int i = blockIdx.x * 256 + threadIdx.x;      // < Bn*(KP/4) = 81920
    const int b = i / (KP / 4), e4 = (i - b * (KP / 4)) * 4;
    const float in = 1.0f / (float)cnt[b];
    const float* bp = xbarP + ((size_t)b * NRANGE) * KP + e4;
    float sx = 0.f, sy = 0.f, sz = 0.f, sw_ = 0.f;
    #pragma unroll
    for (int rr = 0; rr < NRANGE; ++rr) {
        float4 v = *(const float4*)(bp + rr * KP);
        sx += v.x; sy += v.y; sz += v.z; sw_ += v.w;
    }
    ushort4 o;
    o.x = f2bf(sx * in); o.y = f2bf(sy * in);
    o.z = f2bf(sz * in); o.w = f2bf(sw_ * in);
    *(ushort4*)&xsg[(size_t)b * KP + e4] = o;
}

// hbh = bf16(relu(xsg@W1+b1)) via MFMA; x-tile copied into LDS
// (row stride 328 ushorts -> 2-way bank aliasing only = free).
__global__ __launch_bounds__(256) void k2m_h(
        const unsigned short* __restrict__ xsg,
        const unsigned short* __restrict__ w1frag,
        const float* __restrict__ b1, unsigned short* __restrict__ hbh) {
    __shared__ unsigned short xs[16 * 328];    // 10496 B
    const int tid = threadIdx.x;
    const int wave = tid >> 6, lane = tid & 63;
    const int quad = lane >> 4, l15 = lane & 15;
    const int b0 = blockIdx.x * 16;
    for (int i = tid; i < 16 * (KP / 8); i += 256) {
        int row = i / (KP / 8), e8 = (i - row * (KP / 8)) * 8;
        *(uint4*)&xs[row * 328 + e8] = *(const uint4*)&xsg[(size_t)(b0 + row) * KP + e8];
    }
    __syncthreads();
    const int nt = blockIdx.y * 4 + wave;
    if (nt < 50) {
        const unsigned short* arow = xs + l15 * 328 + quad * 8;
        f32x4 acc = {0.f, 0.f, 0.f, 0.f};
        #pragma unroll
        for (int kt = 0; kt < 10; ++kt) {
            bf16x8 a = *(const bf16x8*)(arow + kt * 32);
            bf16x8 bv = *(const bf16x8*)(w1frag + ((size_t)(nt * 10 + kt) * 64 + lane) * 8);
            acc = __builtin_amdgcn_mfma_f32_16x16x32_bf16(a, bv, acc, 0, 0, 0);
        }
        const int col = nt * 16 + l15;
        const float bias = b1[col];
        #pragma unroll
        for (int r = 0; r < 4; ++r) {
            int row = b0 + quad * 4 + r;
            hbh[(size_t)row * Hn + col] = f2bf(fmaxf(acc[r] + bias, 0.f));
        }
    }
}

// mu/lv via MFMA -> LDS (stride 65) -> per-wave softmax/theta/kl epilogue.
__global__ __launch_bounds__(256) void k3_theta(
        const unsigned short* __restrict__ hbh,
        const unsigned short* __restrict__ wfrag,
        const float* __restrict__ bmu, const float* __restrict__ blv,
        float* __restrict__ theta, float* __restrict__ loss) {
    __shared__ float mlds[16 * 65];
    __shared__ float llds[16 * 65];
    const int tid = threadIdx.x;
    const int wave = tid >> 6, lane = tid & 63;
    const int quad = lane >> 4, l15 = lane & 15;
    const int b0 = blockIdx.x * 16;
    const unsigned short* arow = hbh + (size_t)(b0 + l15) * Hn + quad * 8;
    f32x4 am = {0.f, 0.f, 0.f, 0.f}, al = {0.f, 0.f, 0.f, 0.f};
    #pragma unroll
    for (int kt = 0; kt < 25; ++kt) {
        bf16x8 a  = *(const bf16x8*)(arow + kt * 32);
        bf16x8 bm = *(const bf16x8*)(wfrag + ((size_t)(wave * 25 + kt) * 64 + lane) * 8);
        bf16x8 bl = *(const bf16x8*)(wfrag + ((size_t)((4 + wave) * 25 + kt) * 64 + lane) * 8);
        am = __builtin_amdgcn_mfma_f32_16x16x32_bf16(a, bm, am, 0, 0, 0);
        al = __builtin_amdgcn_mfma_f32_16x16x32_bf16(a, bl, al, 0, 0, 0);
    }
    const int t = wave * 16 + l15;                 // 0..63 LDS col
    const float bm_ = (t < Tn) ? bmu[t] : 0.f;
    const float bl_ = (t < Tn) ? blv[t] : 0.f;
    #pragma unroll
    for (int r = 0; r < 4; ++r) {
        int row = quad * 4 + r;
        mlds[row * 65 + t] = am[r] + bm_;
        llds[row * 65 + t] = al[r] + bl_;
    }
    __syncthreads();
    const int tt = (lane < Tn) ? lane : (Tn - 1);
    const bool act = (lane < Tn);
    float klacc = 0.f;
    #pragma unroll
    for (int k = 0; k < 4; ++k) {
        int row = wave * 4 + k;
        float mu = mlds[row * 65 + tt];
        float lv = llds[row * 65 + tt];
        float m = waveReduceMax(act ? mu : -1e30f);
        float ex = act ? expf(mu - m) : 0.f;
        float ssum = waveReduceSum(ex);
        if (act) theta[(b0 + row) * Tn + lane] = ex / ssum;
        klacc += waveReduceSum(act ? (1.f + lv - mu * mu - expf(lv)) : 0.f);
    }
    if (lane == 0) atomicAdd(loss, -0.5f * klacc * (1.0f / (float)Bn));
}

// recon[b] = -sum_tok log( sum_t (theta/Z)[t] * betaU[tok,t] + 1e-5 ).
__global__ __launch_bounds__(256) void k6_recon(
        const int* __restrict__ toks, const int* __restrict__ cnt,
        const float* __restrict__ theta, const float* __restrict__ topicsumR,
        const unsigned short* __restrict__ betaUh, float* __restrict__ loss) {
    __shared__ float sw[Tn];
    __shared__ float swred[4];
    const int b = blockIdx.x, tid = threadIdx.x;
    if (tid < Tn) {
        float z = 0.f;
        #pragma unroll
        for (int j = 0; j < 8; ++j) z += topicsumR[j * 64 + tid];
        sw[tid] = theta[b * Tn + tid] / z;
    }
    __syncthreads();
    float wr[Tn];
    #pragma unroll
    for (int t = 0; t < Tn; ++t) wr[t] = sw[t];
    float lsum = 0.f;
    const int n = cnt[b];
    for (int i = tid; i < n; i += 256) {
        int v = toks[b * Sn + i];
        const uint4* q = (const uint4*)(betaUh + (size_t)v * BSTR);
        float dot = 0.f;
        #pragma unroll
        for (int k = 0; k < 6; ++k) {
            uint4 u = q[k];
            int t = 8 * k;
            dot += wr[t]     * bf_lo(u.x) + wr[t + 1] * bf_hi(u.x);
            dot += wr[t + 2] * bf_lo(u.y) + wr[t + 3] * bf_hi(u.y);
            dot += wr[t + 4] * bf_lo(u.z) + wr[t + 5] * bf_hi(u.z);
            dot += wr[t + 6] * bf_lo(u.w) + wr[t + 7] * bf_hi(u.w);
        }
        unsigned d = ((const unsigned*)q)[24];
        dot += wr[48] * bf_lo(d) + wr[49] * bf_hi(d);
        lsum += logf(dot + 1e-5f);
    }
    float s = waveReduceSum(lsum);
    const int wave = tid >> 6, lane = tid & 63;
    if (lane == 0) swred[wave] = s;
    __syncthreads();
    if (tid == 0) {
        float tot = swred[0] + swred[1] + swred[2] + swred[3];
        atomicAdd(loss, -tot * (1.0f / (float)Bn));
    }
}

extern "C" void kernel_launch(void* const* d_in, const int* in_sizes, int n_in,
                              void* d_out, int out_size, void* d_ws, size_t ws_size,
                              hipStream_t stream) {
    const int*   ids   = (const int*)d_in[0];
    const float* rho   = (const float*)d_in[1];
    const float* alpha = (const float*)d_in[2];
    const float* W1    = (const float*)d_in[3];
    const float* b1    = (const float*)d_in[4];
    const float* Wmu   = (const float*)d_in[5];
    const float* bmu   = (const float*)d_in[6];
    const float* Wlv   = (const float*)d_in[7];
    const float* blv   = (const float*)d_in[8];

    float* theta = (float*)d_out;            // [B, T]
    float* loss  = theta + Bn * Tn;          // scalar at d_out[51200]

    char* w = (char*)d_ws;
    float* topicsumR = (float*)w;               w += 8 * 64 * 4;
    unsigned short* bfrag = (unsigned short*)w; w += 4 * 10 * 64 * 8 * 2;
    unsigned short* w1frag = (unsigned short*)w; w += (size_t)W1FRAG_N * 2;
    unsigned short* wfrag = (unsigned short*)w;  w += (size_t)WFRAG_N * 2;
    int*   cnt      = (int*)w;                  w += Bn * 4;
    int*   toks     = (int*)w;                  w += Bn * Sn * 4;
    float* xbarP    = (float*)w;                w += (size_t)Bn * NRANGE * KP * 4; // 10.5 MB
    unsigned short* hbh = (unsigned short*)w;   w += (size_t)Bn * Hn * 2;
    unsigned short* rhoh = (unsigned short*)w;  w += (size_t)Vn * KP * 2;   // 32 MB
    unsigned int* betaU32 = (unsigned int*)w;   w += (size_t)Vn * 128;      // 6.4 MB
    unsigned short* xsg = (unsigned short*)w;   w += (size_t)Bn * KP * 2;   // 0.66 MB

    const int k0grid = (W1FRAG_N + WFRAG_N + 255) / 256;   // 1400
    ka_init<<<CASTB + k0grid, 256, 0, stream>>>(
        (const float4*)rho, rhoh, alpha, W1, Wmu, Wlv,
        bfrag, w1frag, wfrag, topicsumR, loss);
    kb_beta_tokens<<<K4B + Bn * NRANGE, 256, 0, stream>>>(
        rhoh, bfrag, betaU32, topicsumR, ids, toks, cnt, xbarP);
    kx_norm<<<Bn * (KP / 4) / 256, 256, 0, stream>>>(xbarP, cnt, xsg);
    k2m_h<<<dim3(64, 13), 256, 0, stream>>>(xsg, w1frag, b1, hbh);
    k3_theta<<<64, 256, 0, stream>>>(hbh, wfrag, bmu, blv, theta, loss);
    k6_recon<<<Bn, 256, 0, stream>>>(toks, cnt, theta, topicsumR,
                                     (const unsigned short*)betaU32, loss);
}

// Round 4
// 201.479 us; speedup vs baseline: 1.0330x; 1.0330x over previous
//
#include <hip/hip_runtime.h>
#include <math.h>

// ETM forward. B=1024 S=512 V=50000 E=300 H=800 T=50.
// ka: [fused] rhoh=bf16(rho) cast (8 floats/thread) + zero topicsumR/loss + B-frags
// kb: [fused] k4 betaU=exp(rhoh@alpha^T) + k1 gather: wave-token-parallel with
//     explicit 4-deep REGISTER prefetch pipeline pinned by sched_barrier(0)
//     (LDS stays 11.7KB -> 8 blocks/CU co-residency preserved, unlike r3 DMA)
// kx: xbar = (sum_r xbarP)/n -> bf16 xsg (once, not 13x inside k2m)
// k2m: hbh = bf16(relu(xsg@W1+b1)) via MFMA
// k3: mu/lv via MFMA -> LDS -> softmax/theta/kl
// k6: recon + loss

#define Bn 1024
#define Sn 512
#define Vn 50000
#define En 300
#define Hn 800
#define Tn 50
#define KP 320             // padded K for E-dim (10 tiles of 32)
#define BSTR 64            // betaU bf16 row stride (ushorts) = 128 B
#define W1FRAG_N (50 * 10 * 64 * 8)
#define WFRAG_N  (8 * 25 * 64 * 8)
#define NRANGE 8
#define VRANGE (Vn / NRANGE)
#define CASTB 7813                             // ceil(Vn*(KP/8)/256)
#define K4B (Vn / 16)                          // 3125 k4 blocks

typedef __bf16 bf16x8 __attribute__((ext_vector_type(8)));
typedef float  f32x4  __attribute__((ext_vector_type(4)));
typedef float  f32x2  __attribute__((ext_vector_type(2)));

__device__ __forceinline__ float waveReduceSum(float v) {
    #pragma unroll
    for (int off = 32; off > 0; off >>= 1) v += __shfl_xor(v, off, 64);
    return v;
}
__device__ __forceinline__ float waveReduceMax(float v) {
    #pragma unroll
    for (int off = 32; off > 0; off >>= 1) v = fmaxf(v, __shfl_xor(v, off, 64));
    return v;
}
__device__ __forceinline__ unsigned short f2bf(float x) {
    unsigned u = __float_as_uint(x);
    return (unsigned short)((u + 0x7FFFu + ((u >> 16) & 1u)) >> 16);
}
__device__ __forceinline__ float bf_lo(unsigned u) { return __uint_as_float(u << 16); }
__device__ __forceinline__ float bf_hi(unsigned u) { return __uint_as_float(u & 0xFFFF0000u); }
__device__ __forceinline__ int lane_prefix(unsigned long long m) {
    return __builtin_amdgcn_mbcnt_hi((unsigned)(m >> 32),
           __builtin_amdgcn_mbcnt_lo((unsigned)m, 0));
}

#define PKACC(u) { \
    c0 += (f32x2){bf_lo((u).x), bf_hi((u).x)}; \
    c1 += (f32x2){bf_lo((u).y), bf_hi((u).y)}; \
    c2 += (f32x2){bf_lo((u).z), bf_hi((u).z)}; \
    c3 += (f32x2){bf_lo((u).w), bf_hi((u).w)}; }

// Fused: blocks [0,CASTB) stream-cast rho->rhoh (8 f32 -> 8 bf16 per thread);
// the rest zero topicsumR/loss and build alpha/W1/[Wmu|Wlv] MFMA B-frags.
__global__ __launch_bounds__(256) void ka_init(
        const float4* __restrict__ rho4, unsigned short* __restrict__ rhoh,
        const float* __restrict__ alpha, const float* __restrict__ W1,
        const float* __restrict__ Wmu, const float* __restrict__ Wlv,
        unsigned short* __restrict__ bfrag, unsigned short* __restrict__ w1frag,
        unsigned short* __restrict__ wfrag, float* __restrict__ topicsumR,
        float* __restrict__ loss) {
    if (blockIdx.x < CASTB) {
        const int i = blockIdx.x * 256 + threadIdx.x;
        if (i < Vn * (KP / 8)) {
            int v = i / (KP / 8), s8 = i - v * (KP / 8);
            int c = s8 * 8;
            ushort4 o0 = {0, 0, 0, 0}, o1 = {0, 0, 0, 0};
            if (c < En) {
                float4 r = rho4[v * (En / 4) + s8 * 2];
                o0.x = f2bf(r.x); o0.y = f2bf(r.y); o0.z = f2bf(r.z); o0.w = f2bf(r.w);
            }
            if (c + 4 < En) {
                float4 r = rho4[v * (En / 4) + s8 * 2 + 1];
                o1.x = f2bf(r.x); o1.y = f2bf(r.y); o1.z = f2bf(r.z); o1.w = f2bf(r.w);
            }
            uint4 st;
            st.x = (unsigned)o0.x | ((unsigned)o0.y << 16);
            st.y = (unsigned)o0.z | ((unsigned)o0.w << 16);
            st.z = (unsigned)o1.x | ((unsigned)o1.y << 16);
            st.w = (unsigned)o1.z | ((unsigned)o1.w << 16);
            *(uint4*)(rhoh + (size_t)v * KP + c) = st;
        }
        return;
    }
    const int gid = (blockIdx.x - CASTB) * 256 + threadIdx.x;
    if (gid < 512) topicsumR[gid] = 0.f;
    if (gid == 520) *loss = 0.f;
    if (gid < 4 * 10 * 64 * 8) {
        int j = gid & 7;
        int lane = (gid >> 3) & 63;
        int rest = gid >> 9;               // w*10 + kt
        int kt = rest % 10, w = rest / 10;
        int t = 16 * w + (lane & 15);
        int e = kt * 32 + (lane >> 4) * 8 + j;
        bfrag[gid] = (t < Tn && e < En) ? f2bf(alpha[t * En + e]) : (unsigned short)0;
    }
    if (gid < W1FRAG_N) {
        int j = gid & 7, lane = (gid >> 3) & 63, rest = gid >> 9;
        int kt = rest % 10, nt = rest / 10;
        int e = kt * 32 + (lane >> 4) * 8 + j;
        int hcol = nt * 16 + (lane & 15);
        w1frag[gid] = (e < En) ? f2bf(W1[e * Hn + hcol]) : (unsigned short)0;
    } else {
        int g2 = gid - W1FRAG_N;
        if (g2 < WFRAG_N) {
            int j = g2 & 7, lane = (g2 >> 3) & 63, rest = g2 >> 9;
            int kt = rest % 25, nt = rest / 25;
            int k = kt * 32 + (lane >> 4) * 8 + j;        // < 800 always
            int t = (nt & 3) * 16 + (lane & 15);
            float val = 0.f;
            if (t < Tn) val = (nt < 4) ? Wmu[k * Tn + t] : Wlv[k * Tn + t];
            wfrag[g2] = f2bf(val);
        }
    }
}

// Fused k4+k1: blocks [0,K4B) = betaU MFMA tiles; rest = sliced token gather.
__global__ __launch_bounds__(256) void kb_beta_tokens(
        const unsigned short* __restrict__ rhoh,
        const unsigned short* __restrict__ bfrag,
        unsigned int* __restrict__ betaU32, float* __restrict__ topicsumR,
        const int* __restrict__ ids, int* __restrict__ toks,
        int* __restrict__ cnt, float* __restrict__ xbarP) {
    __shared__ unsigned short trans[16 * 66];   // k4 transpose (2112 B)
    __shared__ __align__(16) int sid[Sn];       // k1 range-filtered tokens
    __shared__ int sfid[Sn];                    // k1 full compaction (r==0)
    __shared__ __align__(16) float xred[4][320];            // 5120 B
    __shared__ int scount, sfull;
    const int tid = threadIdx.x;
    const int wave = tid >> 6, lane = tid & 63;

    if (blockIdx.x < K4B) {
        // ---- k4: betaU tile (16 v), wave = topic tile ----
        const int quad = lane >> 4, l15 = lane & 15;
        const int v0 = blockIdx.x * 16;
        const unsigned short* arow = rhoh + (size_t)(v0 + l15) * KP + quad * 8;
        f32x4 acc = {0.f, 0.f, 0.f, 0.f};
        #pragma unroll
        for (int kt = 0; kt < 10; ++kt) {
            bf16x8 a = *(const bf16x8*)(arow + kt * 32);
            bf16x8 bv = *(const bf16x8*)(bfrag + ((wave * 10 + kt) * 64 + lane) * 8);
            acc = __builtin_amdgcn_mfma_f32_16x16x32_bf16(a, bv, acc, 0, 0, 0);
        }
        float ts = 0.f;
        #pragma unroll
        for (int r = 0; r < 4; ++r) {
            float ev = expf(acc[r]);
            ts += ev;
            trans[(quad * 4 + r) * 66 + 16 * wave + l15] = f2bf(ev);
        }
        ts += __shfl_xor(ts, 16, 64);
        ts += __shfl_xor(ts, 32, 64);
        const int t = 16 * wave + l15;
        if (lane < 16 && t < Tn)
            atomicAdd(&topicsumR[(blockIdx.x & 7) * 64 + t], ts);
        __syncthreads();
        unsigned int* dst = betaU32 + (size_t)v0 * 32;
        const unsigned int* tr32 = (const unsigned int*)trans;
        for (int i = tid; i < 16 * 32; i += 256)
            dst[i] = tr32[(i >> 5) * 33 + (i & 31)];
        return;
    }
    // ---- k1: doc-range gather ----
    const int blk = blockIdx.x - K4B;
    const int r = blk & (NRANGE - 1), b = blk >> 3;
    const int lo = r * VRANGE, hi = lo + VRANGE;
    if (tid == 0) { scount = 0; sfull = 0; }
    __syncthreads();
    // ballot-based compaction: one LDS atomic per wave
    #pragma unroll
    for (int s0 = 0; s0 < Sn; s0 += 256) {
        int id = ids[b * Sn + s0 + tid];
        bool val = (id != 1 && id != 2);
        bool inr = val && id >= lo && id < hi;
        unsigned long long mb = __ballot(inr);
        int pre = lane_prefix(mb);
        int wc = __popcll(mb);
        int base = 0;
        if (lane == 0 && wc) base = atomicAdd(&scount, wc);
        base = __shfl(base, 0, 64);
        if (inr) sid[base + pre] = id;
        if (r == 0) {
            unsigned long long fb = __ballot(val);
            int fpre = lane_prefix(fb);
            int fwc = __popcll(fb);
            int fbase = 0;
            if (lane == 0 && fwc) fbase = atomicAdd(&sfull, fwc);
            fbase = __shfl(fbase, 0, 64);
            if (val) sfid[fbase + fpre] = id;
        }
    }
    __syncthreads();
    if (r == 0) {
        const int nf = sfull;
        for (int i = tid; i < nf; i += 256) toks[b * Sn + i] = sfid[i];
        if (tid == 0) cnt[b] = nf;
    }
    const int m = scount;
    // --- register-pipelined gather: wave w owns tokens s = w, w+4, ...
    //     4 rows (640B, lanes<40 x 16B) in flight via explicit prefetch regs;
    //     sched_barrier(0) pins load-issue before consumption of prev batch.
    f32x2 c0 = {0.f, 0.f}, c1 = {0.f, 0.f}, c2 = {0.f, 0.f}, c3 = {0.f, 0.f};
    if (m > 0 && lane < 40) {
        const uint4* rb = (const uint4*)rhoh;
        const int mm1 = m - 1;
        int s = wave;
        #define LDT(S) rb[(size_t)sid[(S) < mm1 ? (S) : mm1] * 40 + lane]
        uint4 p0 = LDT(s), p1 = LDT(s + 4), p2 = LDT(s + 8), p3 = LDT(s + 12);
        for (; s < m; s += 16) {
            uint4 n0 = LDT(s + 16), n1 = LDT(s + 20),
                  n2 = LDT(s + 24), n3 = LDT(s + 28);
            __builtin_amdgcn_sched_barrier(0);
            PKACC(p0);                      // s < m always here
            if (s + 4 < m)  PKACC(p1);      // wave-uniform branches (scalar)
            if (s + 8 < m)  PKACC(p2);
            if (s + 12 < m) PKACC(p3);
            p0 = n0; p1 = n1; p2 = n2; p3 = n3;
        }
        #undef LDT
        float* xw = &xred[wave][lane * 8];
        *(float4*)(xw)     = (float4){c0[0], c0[1], c1[0], c1[1]};
        *(float4*)(xw + 4) = (float4){c2[0], c2[1], c3[0], c3[1]};
    } else if (lane < 40) {
        float* xw = &xred[wave][lane * 8];
        *(float4*)(xw)     = (float4){0.f, 0.f, 0.f, 0.f};
        *(float4*)(xw + 4) = (float4){0.f, 0.f, 0.f, 0.f};
    }
    __syncthreads();
    float* xbp = xbarP + ((size_t)b * NRANGE + r) * KP;
    for (int c = tid; c < KP; c += 256)
        xbp[c] = xred[0][c] + xred[1][c] + xred[2][c] + xred[3][c];
}

// xsg[b][e] = bf16( (sum_r xbarP[b][r][e]) / cnt[b] )  -- once, not 13x in k2m
__global__ __launch_bounds__(256) void kx_norm(
        const float* __restrict__ xbarP, const int* __restrict__ cnt,
        unsigned short* __restrict__ xsg) {
    const int i = blockIdx.x * 256 + threadIdx.x;      // < Bn*(KP/4) = 81920
    const int b = i / (KP / 4), e4 = (i - b * (KP / 4)) * 4;
    const float in = 1.0f / (float)cnt[b];
    const float* bp = xbarP + ((size_t)b * NRANGE) * KP + e4;
    float sx = 0.f, sy = 0.f, sz = 0.f, sw_ = 0.f;
    #pragma unroll
    for (int rr = 0; rr < NRANGE; ++rr) {
        float4 v = *(const float4*)(bp + rr * KP);
        sx += v.x; sy += v.y; sz += v.z; sw_ += v.w;
    }
    ushort4 o;
    o.x = f2bf(sx * in); o.y = f2bf(sy * in);
    o.z = f2bf(sz * in); o.w = f2bf(sw_ * in);
    *(ushort4*)&xsg[(size_t)b * KP + e4] = o;
}

// hbh = bf16(relu(xsg@W1+b1)) via MFMA; x-tile copied into LDS
// (row stride 328 ushorts -> 2-way bank aliasing only = free).
__global__ __launch_bounds__(256) void k2m_h(
        const unsigned short* __restrict__ xsg,
        const unsigned short* __restrict__ w1frag,
        const float* __restrict__ b1, unsigned short* __restrict__ hbh) {
    __shared__ unsigned short xs[16 * 328];    // 10496 B
    const int tid = threadIdx.x;
    const int wave = tid >> 6, lane = tid & 63;
    const int quad = lane >> 4, l15 = lane & 15;
    const int b0 = blockIdx.x * 16;
    for (int i = tid; i < 16 * (KP / 8); i += 256) {
        int row = i / (KP / 8), e8 = (i - row * (KP / 8)) * 8;
        *(uint4*)&xs[row * 328 + e8] = *(const uint4*)&xsg[(size_t)(b0 + row) * KP + e8];
    }
    __syncthreads();
    const int nt = blockIdx.y * 4 + wave;
    if (nt < 50) {
        const unsigned short* arow = xs + l15 * 328 + quad * 8;
        f32x4 acc = {0.f, 0.f, 0.f, 0.f};
        #pragma unroll
        for (int kt = 0; kt < 10; ++kt) {
            bf16x8 a = *(const bf16x8*)(arow + kt * 32);
            bf16x8 bv = *(const bf16x8*)(w1frag + ((size_t)(nt * 10 + kt) * 64 + lane) * 8);
            acc = __builtin_amdgcn_mfma_f32_16x16x32_bf16(a, bv, acc, 0, 0, 0);
        }
        const int col = nt * 16 + l15;
        const float bias = b1[col];
        #pragma unroll
        for (int r = 0; r < 4; ++r) {
            int row = b0 + quad * 4 + r;
            hbh[(size_t)row * Hn + col] = f2bf(fmaxf(acc[r] + bias, 0.f));
        }
    }
}

// mu/lv via MFMA -> LDS (stride 65) -> per-wave softmax/theta/kl epilogue.
__global__ __launch_bounds__(256) void k3_theta(
        const unsigned short* __restrict__ hbh,
        const unsigned short* __restrict__ wfrag,
        const float* __restrict__ bmu, const float* __restrict__ blv,
        float* __restrict__ theta, float* __restrict__ loss) {
    __shared__ float mlds[16 * 65];
    __shared__ float llds[16 * 65];
    const int tid = threadIdx.x;
    const int wave = tid >> 6, lane = tid & 63;
    const int quad = lane >> 4, l15 = lane & 15;
    const int b0 = blockIdx.x * 16;
    const unsigned short* arow = hbh + (size_t)(b0 + l15) * Hn + quad * 8;
    f32x4 am = {0.f, 0.f, 0.f, 0.f}, al = {0.f, 0.f, 0.f, 0.f};
    #pragma unroll
    for (int kt = 0; kt < 25; ++kt) {
        bf16x8 a  = *(const bf16x8*)(arow + kt * 32);
        bf16x8 bm = *(const bf16x8*)(wfrag + ((size_t)(wave * 25 + kt) * 64 + lane) * 8);
        bf16x8 bl = *(const bf16x8*)(wfrag + ((size_t)((4 + wave) * 25 + kt) * 64 + lane) * 8);
        am = __builtin_amdgcn_mfma_f32_16x16x32_bf16(a, bm, am, 0, 0, 0);
        al = __builtin_amdgcn_mfma_f32_16x16x32_bf16(a, bl, al, 0, 0, 0);
    }
    const int t = wave * 16 + l15;                 // 0..63 LDS col
    const float bm_ = (t < Tn) ? bmu[t] : 0.f;
    const float bl_ = (t < Tn) ? blv[t] : 0.f;
    #pragma unroll
    for (int r = 0; r < 4; ++r) {
        int row = quad * 4 + r;
        mlds[row * 65 + t] = am[r] + bm_;
        llds[row * 65 + t] = al[r] + bl_;
    }
    __syncthreads();
    const int tt = (lane < Tn) ? lane : (Tn - 1);
    const bool act = (lane < Tn);
    float klacc = 0.f;
    #pragma unroll
    for (int k = 0; k < 4; ++k) {
        int row = wave * 4 + k;
        float mu = mlds[row * 65 + tt];
        float lv = llds[row * 65 + tt];
        float m = waveReduceMax(act ? mu : -1e30f);
        float ex = act ? expf(mu - m) : 0.f;
        float ssum = waveReduceSum(ex);
        if (act) theta[(b0 + row) * Tn + lane] = ex / ssum;
        klacc += waveReduceSum(act ? (1.f + lv - mu * mu - expf(lv)) : 0.f);
    }
    if (lane == 0) atomicAdd(loss, -0.5f * klacc * (1.0f / (float)Bn));
}

// recon[b] = -sum_tok log( sum_t (theta/Z)[t] * betaU[tok,t] + 1e-5 ).
__global__ __launch_bounds__(256) void k6_recon(
        const int* __restrict__ toks, const int* __restrict__ cnt,
        const float* __restrict__ theta, const float* __restrict__ topicsumR,
        const unsigned short* __restrict__ betaUh, float* __restrict__ loss) {
    __shared__ float sw[Tn];
    __shared__ float swred[4];
    const int b = blockIdx.x, tid = threadIdx.x;
    if (tid < Tn) {
        float z = 0.f;
        #pragma unroll
        for (int j = 0; j < 8; ++j) z += topicsumR[j * 64 + tid];
        sw[tid] = theta[b * Tn + tid] / z;
    }
    __syncthreads();
    float wr[Tn];
    #pragma unroll
    for (int t = 0; t < Tn; ++t) wr[t] = sw[t];
    float lsum = 0.f;
    const int n = cnt[b];
    for (int i = tid; i < n; i += 256) {
        int v = toks[b * Sn + i];
        const uint4* q = (const uint4*)(betaUh + (size_t)v * BSTR);
        float dot = 0.f;
        #pragma unroll
        for (int k = 0; k < 6; ++k) {
            uint4 u = q[k];
            int t = 8 * k;
            dot += wr[t]     * bf_lo(u.x) + wr[t + 1] * bf_hi(u.x);
            dot += wr[t + 2] * bf_lo(u.y) + wr[t + 3] * bf_hi(u.y);
            dot += wr[t + 4] * bf_lo(u.z) + wr[t + 5] * bf_hi(u.z);
            dot += wr[t + 6] * bf_lo(u.w) + wr[t + 7] * bf_hi(u.w);
        }
        unsigned d = ((const unsigned*)q)[24];
        dot += wr[48] * bf_lo(d) + wr[49] * bf_hi(d);
        lsum += logf(dot + 1e-5f);
    }
    float s = waveReduceSum(lsum);
    const int wave = tid >> 6, lane = tid & 63;
    if (lane == 0) swred[wave] = s;
    __syncthreads();
    if (tid == 0) {
        float tot = swred[0] + swred[1] + swred[2] + swred[3];
        atomicAdd(loss, -tot * (1.0f / (float)Bn));
    }
}

extern "C" void kernel_launch(void* const* d_in, const int* in_sizes, int n_in,
                              void* d_out, int out_size, void* d_ws, size_t ws_size,
                              hipStream_t stream) {
    const int*   ids   = (const int*)d_in[0];
    const float* rho   = (const float*)d_in[1];
    const float* alpha = (const float*)d_in[2];
    const float* W1    = (const float*)d_in[3];
    const float* b1    = (const float*)d_in[4];
    const float* Wmu   = (const float*)d_in[5];
    const float* bmu   = (const float*)d_in[6];
    const float* Wlv   = (const float*)d_in[7];
    const float* blv   = (const float*)d_in[8];

    float* theta = (float*)d_out;            // [B, T]
    float* loss  = theta + Bn * Tn;          // scalar at d_out[51200]

    char* w = (char*)d_ws;
    float* topicsumR = (float*)w;               w += 8 * 64 * 4;
    unsigned short* bfrag = (unsigned short*)w; w += 4 * 10 * 64 * 8 * 2;
    unsigned short* w1frag = (unsigned short*)w; w += (size_t)W1FRAG_N * 2;
    unsigned short* wfrag = (unsigned short*)w;  w += (size_t)WFRAG_N * 2;
    int*   cnt      = (int*)w;                  w += Bn * 4;
    int*   toks     = (int*)w;                  w += Bn * Sn * 4;
    float* xbarP    = (float*)w;                w += (size_t)Bn * NRANGE * KP * 4; // 10.5 MB
    unsigned short* hbh = (unsigned short*)w;   w += (size_t)Bn * Hn * 2;
    unsigned short* rhoh = (unsigned short*)w;  w += (size_t)Vn * KP * 2;   // 32 MB
    unsigned int* betaU32 = (unsigned int*)w;   w += (size_t)Vn * 128;      // 6.4 MB
    unsigned short* xsg = (unsigned short*)w;   w += (size_t)Bn * KP * 2;   // 0.66 MB

    const int k0grid = (W1FRAG_N + WFRAG_N + 255) / 256;   // 1400
    ka_init<<<CASTB + k0grid, 256, 0, stream>>>(
        (const float4*)rho, rhoh, alpha, W1, Wmu, Wlv,
        bfrag, w1frag, wfrag, topicsumR, loss);
    kb_beta_tokens<<<K4B + Bn * NRANGE, 256, 0, stream>>>(
        rhoh, bfrag, betaU32, topicsumR, ids, toks, cnt, xbarP);
    kx_norm<<<Bn * (KP / 4) / 256, 256, 0, stream>>>(xbarP, cnt, xsg);
    k2m_h<<<dim3(64, 13), 256, 0, stream>>>(xsg, w1frag, b1, hbh);
    k3_theta<<<64, 256, 0, stream>>>(hbh, wfrag, bmu, blv, theta, loss);
    k6_recon<<<Bn, 256, 0, stream>>>(toks, cnt, theta, topicsumR,
                                     (const unsigned short*)betaU32, loss);
}

// Round 5
// 199.954 us; speedup vs baseline: 1.0408x; 1.0076x over previous
//
#include <hip/hip_runtime.h>
#include <math.h>

// ETM forward. B=1024 S=512 V=50000 E=300 H=800 T=50.
// ka: [fused] rhoh=bf16(rho) cast + zero topicsumR/loss + B-frags
// kb: [fused] k4 betaU=exp(rhoh@alpha^T) + k1 sliced token gather.
//     XCD-AFFINE: k4 block i -> slice (i%8) of rhoh (tile i/8), k1 slice r
//     -> same XCD (blockIdx%8==r, K4B=3128 mult of 8). Each XCD's working
//     set = its 4MB rhoh slice = its L2 -> gathers hit L2 not L3.
//     k1 gather: inline-asm global_load_dwordx4 double-buffered A/B batches
//     (4 rows each), manual s_waitcnt vmcnt(4)+sched_barrier -> real 8-deep
//     MLP the register allocator can't collapse (r1/r2/r4 all collapsed).
// kx: xbar = (sum_r xbarP)/n -> bf16 xsg
// k2m: hbh = bf16(relu(xsg@W1+b1)) via MFMA
// k3: mu/lv via MFMA -> LDS -> softmax/theta/kl
// k6: recon + loss

#define Bn 1024
#define Sn 512
#define Vn 50000
#define En 300
#define Hn 800
#define Tn 50
#define KP 320             // padded K for E-dim (10 tiles of 32)
#define BSTR 64            // betaU bf16 row stride (ushorts) = 128 B
#define W1FRAG_N (50 * 10 * 64 * 8)
#define WFRAG_N  (8 * 25 * 64 * 8)
#define NRANGE 8
#define CASTB 7813                             // ceil(Vn*(KP/8)/256)
#define K4B 3128                               // 8 x 391 (3125 tiles + 3 idle)

typedef __bf16 bf16x8 __attribute__((ext_vector_type(8)));
typedef float  f32x4  __attribute__((ext_vector_type(4)));
typedef float  f32x2  __attribute__((ext_vector_type(2)));

__device__ __forceinline__ float waveReduceSum(float v) {
    #pragma unroll
    for (int off = 32; off > 0; off >>= 1) v += __shfl_xor(v, off, 64);
    return v;
}
__device__ __forceinline__ float waveReduceMax(float v) {
    #pragma unroll
    for (int off = 32; off > 0; off >>= 1) v = fmaxf(v, __shfl_xor(v, off, 64));
    return v;
}
__device__ __forceinline__ unsigned short f2bf(float x) {
    unsigned u = __float_as_uint(x);
    return (unsigned short)((u + 0x7FFFu + ((u >> 16) & 1u)) >> 16);
}
__device__ __forceinline__ float bf_lo(unsigned u) { return __uint_as_float(u << 16); }
__device__ __forceinline__ float bf_hi(unsigned u) { return __uint_as_float(u & 0xFFFF0000u); }
__device__ __forceinline__ int lane_prefix(unsigned long long m) {
    return __builtin_amdgcn_mbcnt_hi((unsigned)(m >> 32),
           __builtin_amdgcn_mbcnt_lo((unsigned)m, 0));
}
// raw 16B global load with compiler-owned dest reg quad; data valid only
// after a manual s_waitcnt (we count vmcnt ourselves).
__device__ __forceinline__ void gload16a(uint4& d, const uint4* a) {
    asm volatile("global_load_dwordx4 %0, %1, off" : "=v"(d) : "v"(a));
}

#define PKACC(u) { \
    c0 += (f32x2){bf_lo((u).x), bf_hi((u).x)}; \
    c1 += (f32x2){bf_lo((u).y), bf_hi((u).y)}; \
    c2 += (f32x2){bf_lo((u).z), bf_hi((u).z)}; \
    c3 += (f32x2){bf_lo((u).w), bf_hi((u).w)}; }

// Fused: blocks [0,CASTB) stream-cast rho->rhoh (8 f32 -> 8 bf16 per thread);
// the rest zero topicsumR/loss and build alpha/W1/[Wmu|Wlv] MFMA B-frags.
__global__ __launch_bounds__(256) void ka_init(
        const float4* __restrict__ rho4, unsigned short* __restrict__ rhoh,
        const float* __restrict__ alpha, const float* __restrict__ W1,
        const float* __restrict__ Wmu, const float* __restrict__ Wlv,
        unsigned short* __restrict__ bfrag, unsigned short* __restrict__ w1frag,
        unsigned short* __restrict__ wfrag, float* __restrict__ topicsumR,
        float* __restrict__ loss) {
    if (blockIdx.x < CASTB) {
        const int i = blockIdx.x * 256 + threadIdx.x;
        if (i < Vn * (KP / 8)) {
            int v = i / (KP / 8), s8 = i - v * (KP / 8);
            int c = s8 * 8;
            ushort4 o0 = {0, 0, 0, 0}, o1 = {0, 0, 0, 0};
            if (c < En) {
                float4 r = rho4[v * (En / 4) + s8 * 2];
                o0.x = f2bf(r.x); o0.y = f2bf(r.y); o0.z = f2bf(r.z); o0.w = f2bf(r.w);
            }
            if (c + 4 < En) {
                float4 r = rho4[v * (En / 4) + s8 * 2 + 1];
                o1.x = f2bf(r.x); o1.y = f2bf(r.y); o1.z = f2bf(r.z); o1.w = f2bf(r.w);
            }
            uint4 st;
            st.x = (unsigned)o0.x | ((unsigned)o0.y << 16);
            st.y = (unsigned)o0.z | ((unsigned)o0.w << 16);
            st.z = (unsigned)o1.x | ((unsigned)o1.y << 16);
            st.w = (unsigned)o1.z | ((unsigned)o1.w << 16);
            *(uint4*)(rhoh + (size_t)v * KP + c) = st;
        }
        return;
    }
    const int gid = (blockIdx.x - CASTB) * 256 + threadIdx.x;
    if (gid < 512) topicsumR[gid] = 0.f;
    if (gid == 520) *loss = 0.f;
    if (gid < 4 * 10 * 64 * 8) {
        int j = gid & 7;
        int lane = (gid >> 3) & 63;
        int rest = gid >> 9;               // w*10 + kt
        int kt = rest % 10, w = rest / 10;
        int t = 16 * w + (lane & 15);
        int e = kt * 32 + (lane >> 4) * 8 + j;
        bfrag[gid] = (t < Tn && e < En) ? f2bf(alpha[t * En + e]) : (unsigned short)0;
    }
    if (gid < W1FRAG_N) {
        int j = gid & 7, lane = (gid >> 3) & 63, rest = gid >> 9;
        int kt = rest % 10, nt = rest / 10;
        int e = kt * 32 + (lane >> 4) * 8 + j;
        int hcol = nt * 16 + (lane & 15);
        w1frag[gid] = (e < En) ? f2bf(W1[e * Hn + hcol]) : (unsigned short)0;
    } else {
        int g2 = gid - W1FRAG_N;
        if (g2 < WFRAG_N) {
            int j = g2 & 7, lane = (g2 >> 3) & 63, rest = g2 >> 9;
            int kt = rest % 25, nt = rest / 25;
            int k = kt * 32 + (lane >> 4) * 8 + j;        // < 800 always
            int t = (nt & 3) * 16 + (lane & 15);
            float val = 0.f;
            if (t < Tn) val = (nt < 4) ? Wmu[k * Tn + t] : Wlv[k * Tn + t];
            wfrag[g2] = f2bf(val);
        }
    }
}

// Fused k4+k1, XCD-affine: blocks [0,K4B) = betaU MFMA tiles in slice
// (blockIdx%8); rest = sliced token gather on the matching XCD.
__global__ __launch_bounds__(256) void kb_beta_tokens(
        const unsigned short* __restrict__ rhoh,
        const unsigned short* __restrict__ bfrag,
        unsigned int* __restrict__ betaU32, float* __restrict__ topicsumR,
        const int* __restrict__ ids, int* __restrict__ toks,
        int* __restrict__ cnt, float* __restrict__ xbarP) {
    __shared__ unsigned short trans[16 * 66];   // k4 transpose (2112 B)
    __shared__ __align__(16) int sid[Sn];       // k1 range-filtered tokens
    __shared__ int sfid[Sn];                    // k1 full compaction (r==0)
    __shared__ __align__(16) float xred[4][320];            // 5120 B
    __shared__ int scount, sfull;
    const int tid = threadIdx.x;
    const int wave = tid >> 6, lane = tid & 63;

    if (blockIdx.x < K4B) {
        // ---- k4: betaU tile (16 v) inside this XCD's slice ----
        const int x = blockIdx.x & 7;            // XCD == slice
        const int n = blockIdx.x >> 3;           // 0..390
        const int tile = ((x * 3125) >> 3) + n;
        if (tile >= (((x + 1) * 3125) >> 3)) return;    // 390-tile slices idle 1
        const int quad = lane >> 4, l15 = lane & 15;
        const int v0 = tile * 16;
        const unsigned short* arow = rhoh + (size_t)(v0 + l15) * KP + quad * 8;
        f32x4 acc = {0.f, 0.f, 0.f, 0.f};
        #pragma unroll
        for (int kt = 0; kt < 10; ++kt) {
            bf16x8 a = *(const bf16x8*)(arow + kt * 32);
            bf16x8 bv = *(const bf16x8*)(bfrag + ((wave * 10 + kt) * 64 + lane) * 8);
            acc = __builtin_amdgcn_mfma_f32_16x16x32_bf16(a, bv, acc, 0, 0, 0);
        }
        float ts = 0.f;
        #pragma unroll
        for (int r = 0; r < 4; ++r) {
            float ev = expf(acc[r]);
            ts += ev;
            trans[(quad * 4 + r) * 66 + 16 * wave + l15] = f2bf(ev);
        }
        ts += __shfl_xor(ts, 16, 64);
        ts += __shfl_xor(ts, 32, 64);
        const int t = 16 * wave + l15;
        if (lane < 16 && t < Tn)
            atomicAdd(&topicsumR[x * 64 + t], ts);   // replica == XCD (L2-local)
        __syncthreads();
        unsigned int* dst = betaU32 + (size_t)v0 * 32;
        const unsigned int* tr32 = (const unsigned int*)trans;
        for (int i = tid; i < 16 * 32; i += 256)
            dst[i] = tr32[(i >> 5) * 33 + (i & 31)];
        return;
    }
    // ---- k1: doc-range gather (slice r == this XCD; bounds tile-aligned
    //      to match k4's slicing exactly) ----
    const int blk = blockIdx.x - K4B;
    const int r = blk & (NRANGE - 1), b = blk >> 3;
    const int lo = ((r * 3125) >> 3) * 16;
    const int hi = (((r + 1) * 3125) >> 3) * 16;
    if (tid == 0) { scount = 0; sfull = 0; }
    __syncthreads();
    // ballot-based compaction: one LDS atomic per wave
    #pragma unroll
    for (int s0 = 0; s0 < Sn; s0 += 256) {
        int id = ids[b * Sn + s0 + tid];
        bool val = (id != 1 && id != 2);
        bool inr = val && id >= lo && id < hi;
        unsigned long long mb = __ballot(inr);
        int pre = lane_prefix(mb);
        int wc = __popcll(mb);
        int base = 0;
        if (lane == 0 && wc) base = atomicAdd(&scount, wc);
        base = __shfl(base, 0, 64);
        if (inr) sid[base + pre] = id;
        if (r == 0) {
            unsigned long long fb = __ballot(val);
            int fpre = lane_prefix(fb);
            int fwc = __popcll(fb);
            int fbase = 0;
            if (lane == 0 && fwc) fbase = atomicAdd(&sfull, fwc);
            fbase = __shfl(fbase, 0, 64);
            if (val) sfid[fbase + fpre] = id;
        }
    }
    __syncthreads();             // also drains vmcnt -> clean slate for pipeline
    if (r == 0) {
        const int nf = sfull;
        for (int i = tid; i < nf; i += 256) toks[b * Sn + i] = sfid[i];
        if (tid == 0) cnt[b] = nf;
    }
    const int m = scount;
    // --- asm double-buffered gather: wave w owns tokens s = w, w+4, ...
    //     A/B batches of 4 rows (640B, lanes<40 x dwordx4); vmcnt(4) waits
    //     the older batch while the newer 4 loads stay in flight.
    f32x2 c0 = {0.f, 0.f}, c1 = {0.f, 0.f}, c2 = {0.f, 0.f}, c3 = {0.f, 0.f};
    if (m > 0 && lane < 40) {
        const uint4* rb = (const uint4*)rhoh;
        const int mm1 = m - 1;
        uint4 A0, A1, A2, A3, B0, B1, B2, B3;
        #define ADDR(S) (rb + (size_t)sid[(S) < mm1 ? (S) : mm1] * 40 + lane)
        int s = wave;
        gload16a(A0, ADDR(s));      gload16a(A1, ADDR(s + 4));
        gload16a(A2, ADDR(s + 8));  gload16a(A3, ADDR(s + 12));
        for (;;) {
            gload16a(B0, ADDR(s + 16)); gload16a(B1, ADDR(s + 20));
            gload16a(B2, ADDR(s + 24)); gload16a(B3, ADDR(s + 28));
            asm volatile("s_waitcnt vmcnt(4)" ::: "memory");
            __builtin_amdgcn_sched_barrier(0);
            if (s < m)      PKACC(A0);
            if (s + 4 < m)  PKACC(A1);
            if (s + 8 < m)  PKACC(A2);
            if (s + 12 < m) PKACC(A3);
            s += 16;
            if (s >= m) break;
            gload16a(A0, ADDR(s + 16)); gload16a(A1, ADDR(s + 20));
            gload16a(A2, ADDR(s + 24)); gload16a(A3, ADDR(s + 28));
            asm volatile("s_waitcnt vmcnt(4)" ::: "memory");
            __builtin_amdgcn_sched_barrier(0);
            if (s < m)      PKACC(B0);
            if (s + 4 < m)  PKACC(B1);
            if (s + 8 < m)  PKACC(B2);
            if (s + 12 < m) PKACC(B3);
            s += 16;
            if (s >= m) break;
        }
        #undef ADDR
    }
    if (lane < 40) {
        float* xw = &xred[wave][lane * 8];
        *(float4*)(xw)     = (float4){c0[0], c0[1], c1[0], c1[1]};
        *(float4*)(xw + 4) = (float4){c2[0], c2[1], c3[0], c3[1]};
    }
    __syncthreads();             // drains leftover clamped prefetch loads
    float* xbp = xbarP + ((size_t)b * NRANGE + r) * KP;
    for (int c = tid; c < KP; c += 256)
        xbp[c] = xred[0][c] + xred[1][c] + xred[2][c] + xred[3][c];
}

// xsg[b][e] = bf16( (sum_r xbarP[b][r][e]) / cnt[b] )  -- once, not 13x in k2m
__global__ __launch_bounds__(256) void kx_norm(
        const float* __restrict__ xbarP, const int* __restrict__ cnt,
        unsigned short* __restrict__ xsg) {
    const int i = blockIdx.x * 256 + threadIdx.x;      // < Bn*(KP/4) = 81920
    const int b = i / (KP / 4), e4 = (i - b * (KP / 4)) * 4;
    const float in = 1.0f / (float)cnt[b];
    const float* bp = xbarP + ((size_t)b * NRANGE) * KP + e4;
    float sx = 0.f, sy = 0.f, sz = 0.f, sw_ = 0.f;
    #pragma unroll
    for (int rr = 0; rr < NRANGE; ++rr) {
        float4 v = *(const float4*)(bp + rr * KP);
        sx += v.x; sy += v.y; sz += v.z; sw_ += v.w;
    }
    ushort4 o;
    o.x = f2bf(sx * in); o.y = f2bf(sy * in);
    o.z = f2bf(sz * in); o.w = f2bf(sw_ * in);
    *(ushort4*)&xsg[(size_t)b * KP + e4] = o;
}

// hbh = bf16(relu(xsg@W1+b1)) via MFMA; x-tile copied into LDS
// (row stride 328 ushorts -> 2-way bank aliasing only = free).
__global__ __launch_bounds__(256) void k2m_h(
        const unsigned short* __restrict__ xsg,
        const unsigned short* __restrict__ w1frag,
        const float* __restrict__ b1, unsigned short* __restrict__ hbh) {
    __shared__ unsigned short xs[16 * 328];    // 10496 B
    const int tid = threadIdx.x;
    const int wave = tid >> 6, lane = tid & 63;
    const int quad = lane >> 4, l15 = lane & 15;
    const int b0 = blockIdx.x * 16;
    for (int i = tid; i < 16 * (KP / 8); i += 256) {
        int row = i / (KP / 8), e8 = (i - row * (KP / 8)) * 8;
        *(uint4*)&xs[row * 328 + e8] = *(const uint4*)&xsg[(size_t)(b0 + row) * KP + e8];
    }
    __syncthreads();
    const int nt = blockIdx.y * 4 + wave;
    if (nt < 50) {
        const unsigned short* arow = xs + l15 * 328 + quad * 8;
        f32x4 acc = {0.f, 0.f, 0.f, 0.f};
        #pragma unroll
        for (int kt = 0; kt < 10; ++kt) {
            bf16x8 a = *(const bf16x8*)(arow + kt * 32);
            bf16x8 bv = *(const bf16x8*)(w1frag + ((size_t)(nt * 10 + kt) * 64 + lane) * 8);
            acc = __builtin_amdgcn_mfma_f32_16x16x32_bf16(a, bv, acc, 0, 0, 0);
        }
        const int col = nt * 16 + l15;
        const float bias = b1[col];
        #pragma unroll
        for (int r = 0; r < 4; ++r) {
            int row = b0 + quad * 4 + r;
            hbh[(size_t)row * Hn + col] = f2bf(fmaxf(acc[r] + bias, 0.f));
        }
    }
}

// mu/lv via MFMA -> LDS (stride 65) -> per-wave softmax/theta/kl epilogue.
__global__ __launch_bounds__(256) void k3_theta(
        const unsigned short* __restrict__ hbh,
        const unsigned short* __restrict__ wfrag,
        const float* __restrict__ bmu, const float* __restrict__ blv,
        float* __restrict__ theta, float* __restrict__ loss) {
    __shared__ float mlds[16 * 65];
    __shared__ float llds[16 * 65];
    const int tid = threadIdx.x;
    const int wave = tid >> 6, lane = tid & 63;
    const int quad = lane >> 4, l15 = lane & 15;
    const int b0 = blockIdx.x * 16;
    const unsigned short* arow = hbh + (size_t)(b0 + l15) * Hn + quad * 8;
    f32x4 am = {0.f, 0.f, 0.f, 0.f}, al = {0.f, 0.f, 0.f, 0.f};
    #pragma unroll
    for (int kt = 0; kt < 25; ++kt) {
        bf16x8 a  = *(const bf16x8*)(arow + kt * 32);
        bf16x8 bm = *(const bf16x8*)(wfrag + ((size_t)(wave * 25 + kt) * 64 + lane) * 8);
        bf16x8 bl = *(const bf16x8*)(wfrag + ((size_t)((4 + wave) * 25 + kt) * 64 + lane) * 8);
        am = __builtin_amdgcn_mfma_f32_16x16x32_bf16(a, bm, am, 0, 0, 0);
        al = __builtin_amdgcn_mfma_f32_16x16x32_bf16(a, bl, al, 0, 0, 0);
    }
    const int t = wave * 16 + l15;                 // 0..63 LDS col
    const float bm_ = (t < Tn) ? bmu[t] : 0.f;
    const float bl_ = (t < Tn) ? blv[t] : 0.f;
    #pragma unroll
    for (int r = 0; r < 4; ++r) {
        int row = quad * 4 + r;
        mlds[row * 65 + t] = am[r] + bm_;
        llds[row * 65 + t] = al[r] + bl_;
    }
    __syncthreads();
    const int tt = (lane < Tn) ? lane : (Tn - 1);
    const bool act = (lane < Tn);
    float klacc = 0.f;
    #pragma unroll
    for (int k = 0; k < 4; ++k) {
        int row = wave * 4 + k;
        float mu = mlds[row * 65 + tt];
        float lv = llds[row * 65 + tt];
        float m = waveReduceMax(act ? mu : -1e30f);
        float ex = act ? expf(mu - m) : 0.f;
        float ssum = waveReduceSum(ex);
        if (act) theta[(b0 + row) * Tn + lane] = ex / ssum;
        klacc += waveReduceSum(act ? (1.f + lv - mu * mu - expf(lv)) : 0.f);
    }
    if (lane == 0) atomicAdd(loss, -0.5f * klacc * (1.0f / (float)Bn));
}

// recon[b] = -sum_tok log( sum_t (theta/Z)[t] * betaU[tok,t] + 1e-5 ).
__global__ __launch_bounds__(256) void k6_recon(
        const int* __restrict__ toks, const int* __restrict__ cnt,
        const float* __restrict__ theta, const float* __restrict__ topicsumR,
        const unsigned short* __restrict__ betaUh, float* __restrict__ loss) {
    __shared__ float sw[Tn];
    __shared__ float swred[4];
    const int b = blockIdx.x, tid = threadIdx.x;
    if (tid < Tn) {
        float z = 0.f;
        #pragma unroll
        for (int j = 0; j < 8; ++j) z += topicsumR[j * 64 + tid];
        sw[tid] = theta[b * Tn + tid] / z;
    }
    __syncthreads();
    float wr[Tn];
    #pragma unroll
    for (int t = 0; t < Tn; ++t) wr[t] = sw[t];
    float lsum = 0.f;
    const int n = cnt[b];
    for (int i = tid; i < n; i += 256) {
        int v = toks[b * Sn + i];
        const uint4* q = (const uint4*)(betaUh + (size_t)v * BSTR);
        float dot = 0.f;
        #pragma unroll
        for (int k = 0; k < 6; ++k) {
            uint4 u = q[k];
            int t = 8 * k;
            dot += wr[t]     * bf_lo(u.x) + wr[t + 1] * bf_hi(u.x);
            dot += wr[t + 2] * bf_lo(u.y) + wr[t + 3] * bf_hi(u.y);
            dot += wr[t + 4] * bf_lo(u.z) + wr[t + 5] * bf_hi(u.z);
            dot += wr[t + 6] * bf_lo(u.w) + wr[t + 7] * bf_hi(u.w);
        }
        unsigned d = ((const unsigned*)q)[24];
        dot += wr[48] * bf_lo(d) + wr[49] * bf_hi(d);
        lsum += logf(dot + 1e-5f);
    }
    float s = waveReduceSum(lsum);
    const int wave = tid >> 6, lane = tid & 63;
    if (lane == 0) swred[wave] = s;
    __syncthreads();
    if (tid == 0) {
        float tot = swred[0] + swred[1] + swred[2] + swred[3];
        atomicAdd(loss, -tot * (1.0f / (float)Bn));
    }
}

extern "C" void kernel_launch(void* const* d_in, const int* in_sizes, int n_in,
                              void* d_out, int out_size, void* d_ws, size_t ws_size,
                              hipStream_t stream) {
    const int*   ids   = (const int*)d_in[0];
    const float* rho   = (const float*)d_in[1];
    const float* alpha = (const float*)d_in[2];
    const float* W1    = (const float*)d_in[3];
    const float* b1    = (const float*)d_in[4];
    const float* Wmu   = (const float*)d_in[5];
    const float* bmu   = (const float*)d_in[6];
    const float* Wlv   = (const float*)d_in[7];
    const float* blv   = (const float*)d_in[8];

    float* theta = (float*)d_out;            // [B, T]
    float* loss  = theta + Bn * Tn;          // scalar at d_out[51200]

    char* w = (char*)d_ws;
    float* topicsumR = (float*)w;               w += 8 * 64 * 4;
    unsigned short* bfrag = (unsigned short*)w; w += 4 * 10 * 64 * 8 * 2;
    unsigned short* w1frag = (unsigned short*)w; w += (size_t)W1FRAG_N * 2;
    unsigned short* wfrag = (unsigned short*)w;  w += (size_t)WFRAG_N * 2;
    int*   cnt      = (int*)w;                  w += Bn * 4;
    int*   toks     = (int*)w;                  w += Bn * Sn * 4;
    float* xbarP    = (float*)w;                w += (size_t)Bn * NRANGE * KP * 4; // 10.5 MB
    unsigned short* hbh = (unsigned short*)w;   w += (size_t)Bn * Hn * 2;
    unsigned short* rhoh = (unsigned short*)w;  w += (size_t)Vn * KP * 2;   // 32 MB
    unsigned int* betaU32 = (unsigned int*)w;   w += (size_t)Vn * 128;      // 6.4 MB
    unsigned short* xsg = (unsigned short*)w;   w += (size_t)Bn * KP * 2;   // 0.66 MB

    const int k0grid = (W1FRAG_N + WFRAG_N + 255) / 256;   // 1400
    ka_init<<<CASTB + k0grid, 256, 0, stream>>>(
        (const float4*)rho, rhoh, alpha, W1, Wmu, Wlv,
        bfrag, w1frag, wfrag, topicsumR, loss);
    kb_beta_tokens<<<K4B + Bn * NRANGE, 256, 0, stream>>>(
        rhoh, bfrag, betaU32, topicsumR, ids, toks, cnt, xbarP);
    kx_norm<<<Bn * (KP / 4) / 256, 256, 0, stream>>>(xbarP, cnt, xsg);
    k2m_h<<<dim3(64, 13), 256, 0, stream>>>(xsg, w1frag, b1, hbh);
    k3_theta<<<64, 256, 0, stream>>>(hbh, wfrag, bmu, blv, theta, loss);
    k6_recon<<<Bn, 256, 0, stream>>>(toks, cnt, theta, topicsumR,
                                     (const unsigned short*)betaU32, loss);
}